// Round 1
// baseline (1089.612 us; speedup 1.0000x reference)
//
#include <hip/hip_runtime.h>
#include <math.h>

#define DD 512
#define NH 8
#define HD 64
#define NLQ 2048
#define NLK 8192

// ---------------------------------------------------------------------------
// GEMM: Y[r][o] = sum_c X[r][c] * W[o][c] + b[o]
// X: [nrows][512], W: [512][512] row-major, Y: [nrows][512]
// 128x128 tile, 256 threads, 8x8 per thread, K-chunk 16.
// ---------------------------------------------------------------------------
__global__ __launch_bounds__(256) void gemm_wt(const float* __restrict__ X,
                                               const float* __restrict__ W,
                                               const float* __restrict__ b,
                                               float* __restrict__ Y,
                                               int nrows)
{
    __shared__ float Xs[16][132];
    __shared__ float Ws[16][132];
    const int r0 = blockIdx.x * 128;
    const int o0 = blockIdx.y * 128;
    if (r0 >= nrows) return;
    const int t    = threadIdx.x;
    const int tx   = t & 15;
    const int ty   = t >> 4;
    const int scg  = (t & 3) * 4;  // staging c offset (0,4,8,12)
    const int srow = t >> 2;       // staging row 0..63

    float acc[8][8];
#pragma unroll
    for (int i = 0; i < 8; ++i)
#pragma unroll
        for (int j = 0; j < 8; ++j) acc[i][j] = 0.f;

    for (int kc = 0; kc < DD; kc += 16) {
        __syncthreads();
#pragma unroll
        for (int p = 0; p < 2; ++p) {
            const int r = srow + p * 64;
            const float4 xv = *(const float4*)&X[(size_t)(r0 + r) * DD + kc + scg];
            Xs[scg + 0][r] = xv.x; Xs[scg + 1][r] = xv.y;
            Xs[scg + 2][r] = xv.z; Xs[scg + 3][r] = xv.w;
            const float4 wv = *(const float4*)&W[(size_t)(o0 + r) * DD + kc + scg];
            Ws[scg + 0][r] = wv.x; Ws[scg + 1][r] = wv.y;
            Ws[scg + 2][r] = wv.z; Ws[scg + 3][r] = wv.w;
        }
        __syncthreads();
#pragma unroll
        for (int c = 0; c < 16; ++c) {
            const float4 x0 = *(const float4*)&Xs[c][ty * 8];
            const float4 x1 = *(const float4*)&Xs[c][ty * 8 + 4];
            const float4 w0 = *(const float4*)&Ws[c][tx * 8];
            const float4 w1 = *(const float4*)&Ws[c][tx * 8 + 4];
            const float xr[8] = {x0.x, x0.y, x0.z, x0.w, x1.x, x1.y, x1.z, x1.w};
            const float wr[8] = {w0.x, w0.y, w0.z, w0.w, w1.x, w1.y, w1.z, w1.w};
#pragma unroll
            for (int i = 0; i < 8; ++i)
#pragma unroll
                for (int j = 0; j < 8; ++j)
                    acc[i][j] = fmaf(xr[i], wr[j], acc[i][j]);
        }
    }
#pragma unroll
    for (int i = 0; i < 8; ++i) {
        const int r = r0 + ty * 8 + i;
#pragma unroll
        for (int j = 0; j < 8; j += 4) {
            const int o = o0 + tx * 8 + j;
            float4 ov;
            ov.x = acc[i][j + 0] + b[o + 0];
            ov.y = acc[i][j + 1] + b[o + 1];
            ov.z = acc[i][j + 2] + b[o + 2];
            ov.w = acc[i][j + 3] + b[o + 3];
            *(float4*)&Y[(size_t)r * DD + o] = ov;
        }
    }
}

// ---------------------------------------------------------------------------
// Fused flash attention (fp32, exact within ~2e-5 of reference semantics;
// clamp(-20,20) floor and masked-key e^-20 weights provably negligible).
// Block: 256 thr = 4 waves; wave owns 16 queries of a 64-query tile, one head.
// KT=64 key tile, register-double-buffered K/V staging.
// Lane tile: 4q x 4k (QK) / 4q x 4d (PV) -> 16 FMA per 2 ds_read_b128.
// Grid (head, qtile) head-fastest so blocks sharing bias rows co-schedule.
// ---------------------------------------------------------------------------
#define QT 64
#define KT 64
#define SP 68  // padded LDS row stride (floats); 68*4 bytes keeps 16B alignment

__global__ __launch_bounds__(256) void attn_fused(const float* __restrict__ qp,
                                                  const float* __restrict__ kp,
                                                  const float* __restrict__ vp,
                                                  const float* __restrict__ bias,
                                                  const int* __restrict__ mask,
                                                  float* __restrict__ ao)
{
    __shared__ float qs[HD][SP];  // [d][q]
    __shared__ float ks[HD][SP];  // [d][k]
    __shared__ float vs[KT][HD];  // [k][d]
    __shared__ float ps[KT][SP];  // [k][q]

    const int h    = blockIdx.x;
    const int q0   = blockIdx.y * QT;
    const int t    = threadIdx.x;
    const int lane = t & 63;
    const int wq0  = (t >> 6) * 16;    // wave's q offset in tile
    const int qg   = lane >> 4;        // 0..3
    const int kg   = lane & 15;        // 0..15 (k-group in QK, d-group in PV)
    const int qloc = wq0 + qg * 4;     // 0..60

    const int sr  = t >> 2;            // staging row 0..63
    const int sd0 = (t & 3) * 4;       // staging d base (+p*16)

    // stage Q tile -> qs[d][q] (transposed)
#pragma unroll
    for (int p = 0; p < 4; ++p) {
        const int d = sd0 + p * 16;
        const float4 v = *(const float4*)&qp[(size_t)(q0 + sr) * DD + h * HD + d];
        qs[d + 0][sr] = v.x; qs[d + 1][sr] = v.y;
        qs[d + 2][sr] = v.z; qs[d + 3][sr] = v.w;
    }

    // preload K/V tile 0 into registers
    float4 kreg[4], vreg[4];
#pragma unroll
    for (int p = 0; p < 4; ++p) {
        const int d = sd0 + p * 16;
        kreg[p] = *(const float4*)&kp[(size_t)sr * DD + h * HD + d];
        vreg[p] = *(const float4*)&vp[(size_t)sr * DD + h * HD + d];
    }

    float m[4] = {-INFINITY, -INFINITY, -INFINITY, -INFINITY};
    float l[4] = {0.f, 0.f, 0.f, 0.f};
    float acc[4][4];
#pragma unroll
    for (int i = 0; i < 4; ++i)
#pragma unroll
        for (int j = 0; j < 4; ++j) acc[i][j] = 0.f;

    for (int kt = 0; kt < NLK; kt += KT) {
        __syncthreads();  // previous tile's LDS reads done (also covers qs)
        // registers -> LDS
#pragma unroll
        for (int p = 0; p < 4; ++p) {
            const int d = sd0 + p * 16;
            ks[d + 0][sr] = kreg[p].x; ks[d + 1][sr] = kreg[p].y;
            ks[d + 2][sr] = kreg[p].z; ks[d + 3][sr] = kreg[p].w;
            *(float4*)&vs[sr][d] = vreg[p];
        }
        __syncthreads();

        // prefetch next K/V tile (latency hidden under QK+PV compute)
        if (kt + KT < NLK) {
#pragma unroll
            for (int p = 0; p < 4; ++p) {
                const int d = sd0 + p * 16;
                kreg[p] = *(const float4*)&kp[(size_t)(kt + KT + sr) * DD + h * HD + d];
                vreg[p] = *(const float4*)&vp[(size_t)(kt + KT + sr) * DD + h * HD + d];
            }
        }

        // bias + mask for this tile (global, hidden under QK d-loop)
        float4 breg[4];
#pragma unroll
        for (int i = 0; i < 4; ++i)
            breg[i] = *(const float4*)&bias[(size_t)(q0 + qloc + i) * NLK + kt + kg * 4];
        const int4 mreg = *(const int4*)&mask[kt + kg * 4];

        // QK^T: s[4q][4k]
        float s[4][4];
#pragma unroll
        for (int i = 0; i < 4; ++i)
#pragma unroll
            for (int j = 0; j < 4; ++j) s[i][j] = 0.f;

#pragma unroll 4
        for (int d = 0; d < HD; ++d) {
            const float4 qv = *(const float4*)&qs[d][qloc];
            const float4 kv = *(const float4*)&ks[d][kg * 4];
            const float qa[4] = {qv.x, qv.y, qv.z, qv.w};
            const float ka[4] = {kv.x, kv.y, kv.z, kv.w};
#pragma unroll
            for (int i = 0; i < 4; ++i)
#pragma unroll
                for (int j = 0; j < 4; ++j)
                    s[i][j] = fmaf(qa[i], ka[j], s[i][j]);
        }

        const float mk[4] = {mreg.x ? -10000.f : 0.f, mreg.y ? -10000.f : 0.f,
                             mreg.z ? -10000.f : 0.f, mreg.w ? -10000.f : 0.f};
        const float ba[4][4] = {
            {breg[0].x, breg[0].y, breg[0].z, breg[0].w},
            {breg[1].x, breg[1].y, breg[1].z, breg[1].w},
            {breg[2].x, breg[2].y, breg[2].z, breg[2].w},
            {breg[3].x, breg[3].y, breg[3].z, breg[3].w}};
#pragma unroll
        for (int i = 0; i < 4; ++i)
#pragma unroll
            for (int j = 0; j < 4; ++j)
                s[i][j] = fmaf(s[i][j], 0.125f, ba[i][j] + mk[j]);

        // online softmax (rows live across the 16 lanes of this qg group)
#pragma unroll
        for (int i = 0; i < 4; ++i) {
            float tm = fmaxf(fmaxf(s[i][0], s[i][1]), fmaxf(s[i][2], s[i][3]));
            tm = fmaxf(tm, __shfl_xor(tm, 1));
            tm = fmaxf(tm, __shfl_xor(tm, 2));
            tm = fmaxf(tm, __shfl_xor(tm, 4));
            tm = fmaxf(tm, __shfl_xor(tm, 8));
            const float mn = fmaxf(m[i], tm);
            const float sc = __expf(m[i] - mn);
            m[i] = mn;
            float ts = 0.f;
#pragma unroll
            for (int j = 0; j < 4; ++j) {
                s[i][j] = __expf(s[i][j] - mn);
                ts += s[i][j];
            }
            ts += __shfl_xor(ts, 1);
            ts += __shfl_xor(ts, 2);
            ts += __shfl_xor(ts, 4);
            ts += __shfl_xor(ts, 8);
            l[i] = l[i] * sc + ts;
#pragma unroll
            for (int j = 0; j < 4; ++j) acc[i][j] *= sc;
#pragma unroll
            for (int j = 0; j < 4; ++j) ps[kg * 4 + j][qloc + i] = s[i][j];
        }

        // PV: acc[4q][4d] += P[q][k] * V[k][d]   (wave reads only its own q cols)
#pragma unroll 4
        for (int kk = 0; kk < KT; ++kk) {
            const float4 pv = *(const float4*)&ps[kk][qloc];
            const float4 vv = *(const float4*)&vs[kk][kg * 4];
            const float pa[4] = {pv.x, pv.y, pv.z, pv.w};
            const float va[4] = {vv.x, vv.y, vv.z, vv.w};
#pragma unroll
            for (int i = 0; i < 4; ++i)
#pragma unroll
                for (int j = 0; j < 4; ++j)
                    acc[i][j] = fmaf(pa[i], va[j], acc[i][j]);
        }
    }

    // finalize: ao[q][h*64 + d]
#pragma unroll
    for (int i = 0; i < 4; ++i) {
        const float inv = 1.f / l[i];
        float4 ov;
        ov.x = acc[i][0] * inv;
        ov.y = acc[i][1] * inv;
        ov.z = acc[i][2] * inv;
        ov.w = acc[i][3] * inv;
        *(float4*)&ao[(size_t)(q0 + qloc + i) * DD + h * HD + kg * 4] = ov;
    }
}

extern "C" void kernel_launch(void* const* d_in, const int* in_sizes, int n_in,
                              void* d_out, int out_size, void* d_ws, size_t ws_size,
                              hipStream_t stream)
{
    (void)in_sizes; (void)n_in; (void)out_size; (void)ws_size;
    const float* Q    = (const float*)d_in[0];
    const float* K    = (const float*)d_in[1];
    const float* V    = (const float*)d_in[2];
    const int*   mask = (const int*)d_in[3];
    const float* bias = (const float*)d_in[4];
    const float* Win  = (const float*)d_in[5];
    const float* bin  = (const float*)d_in[6];
    const float* Wout = (const float*)d_in[7];
    const float* bout = (const float*)d_in[8];
    float* out = (float*)d_out;

    // workspace: qp | kp | vp | ao   (40 MB total, fp32)
    float* qp = (float*)d_ws;
    float* kp = qp + (size_t)NLQ * DD;
    float* vp = kp + (size_t)NLK * DD;
    float* ao = vp + (size_t)NLK * DD;

    gemm_wt<<<dim3(NLQ / 128, 4), 256, 0, stream>>>(Q, Win,              bin,          qp, NLQ);
    gemm_wt<<<dim3(NLK / 128, 4), 256, 0, stream>>>(K, Win + DD * DD,    bin + DD,     kp, NLK);
    gemm_wt<<<dim3(NLK / 128, 4), 256, 0, stream>>>(V, Win + 2 * DD * DD, bin + 2 * DD, vp, NLK);
    attn_fused<<<dim3(NH, NLQ / QT), 256, 0, stream>>>(qp, kp, vp, bias, mask, ao);
    gemm_wt<<<dim3(NLQ / 128, 4), 256, 0, stream>>>(ao, Wout, bout, out, NLQ);
}

// Round 2
// 582.714 us; speedup vs baseline: 1.8699x; 1.8699x over previous
//
#include <hip/hip_runtime.h>
#include <math.h>

#define DD 512
#define NH 8
#define HD 64
#define NLQ 2048
#define NLK 8192

typedef __attribute__((ext_vector_type(8))) short bf16x8;
typedef __attribute__((ext_vector_type(4))) float f32x4;

#define MFMA16(a, b, c) __builtin_amdgcn_mfma_f32_16x16x32_bf16((a), (b), (c), 0, 0, 0)

__device__ __forceinline__ unsigned short f2bf(float x) {
    unsigned u = __builtin_bit_cast(unsigned, x);
    u += 0x7fffu + ((u >> 16) & 1u);
    return (unsigned short)(u >> 16);
}
__device__ __forceinline__ float bf2f(unsigned short h) {
    unsigned u = ((unsigned)h) << 16;
    return __builtin_bit_cast(float, u);
}

// ---------------------------------------------------------------------------
// GEMM: Y[r][o] = sum_c X[r][c] * W[o][c] + b[o]
// MODE 0: write f32 Y rows. MODE 1: write bf16 hi/lo rows (Yhi/Ylo [nrows][512]).
// MODE 2: write bf16 hi/lo TRANSPOSED (Yhi/Ylo [512][nrows]).
// ---------------------------------------------------------------------------
template <int MODE>
__global__ __launch_bounds__(256) void gemm_wt(const float* __restrict__ X,
                                               const float* __restrict__ W,
                                               const float* __restrict__ b,
                                               float* __restrict__ Y,
                                               short* __restrict__ Yhi,
                                               short* __restrict__ Ylo,
                                               int nrows)
{
    __shared__ float Xs[16][132];
    __shared__ float Ws[16][132];
    const int r0 = blockIdx.x * 128;
    const int o0 = blockIdx.y * 128;
    const int t    = threadIdx.x;
    const int tx   = t & 15;
    const int ty   = t >> 4;
    const int scg  = (t & 3) * 4;
    const int srow = t >> 2;

    float acc[8][8];
#pragma unroll
    for (int i = 0; i < 8; ++i)
#pragma unroll
        for (int j = 0; j < 8; ++j) acc[i][j] = 0.f;

    for (int kc = 0; kc < DD; kc += 16) {
        __syncthreads();
#pragma unroll
        for (int p = 0; p < 2; ++p) {
            const int r = srow + p * 64;
            const float4 xv = *(const float4*)&X[(size_t)(r0 + r) * DD + kc + scg];
            Xs[scg + 0][r] = xv.x; Xs[scg + 1][r] = xv.y;
            Xs[scg + 2][r] = xv.z; Xs[scg + 3][r] = xv.w;
            const float4 wv = *(const float4*)&W[(size_t)(o0 + r) * DD + kc + scg];
            Ws[scg + 0][r] = wv.x; Ws[scg + 1][r] = wv.y;
            Ws[scg + 2][r] = wv.z; Ws[scg + 3][r] = wv.w;
        }
        __syncthreads();
#pragma unroll
        for (int c = 0; c < 16; ++c) {
            const float4 x0 = *(const float4*)&Xs[c][ty * 8];
            const float4 x1 = *(const float4*)&Xs[c][ty * 8 + 4];
            const float4 w0 = *(const float4*)&Ws[c][tx * 8];
            const float4 w1 = *(const float4*)&Ws[c][tx * 8 + 4];
            const float xr[8] = {x0.x, x0.y, x0.z, x0.w, x1.x, x1.y, x1.z, x1.w};
            const float wr[8] = {w0.x, w0.y, w0.z, w0.w, w1.x, w1.y, w1.z, w1.w};
#pragma unroll
            for (int i = 0; i < 8; ++i)
#pragma unroll
                for (int j = 0; j < 8; ++j)
                    acc[i][j] = fmaf(xr[i], wr[j], acc[i][j]);
        }
    }

    if (MODE == 0) {
#pragma unroll
        for (int i = 0; i < 8; ++i) {
            const int r = r0 + ty * 8 + i;
#pragma unroll
            for (int j = 0; j < 8; j += 4) {
                const int o = o0 + tx * 8 + j;
                float4 ov;
                ov.x = acc[i][j + 0] + b[o + 0];
                ov.y = acc[i][j + 1] + b[o + 1];
                ov.z = acc[i][j + 2] + b[o + 2];
                ov.w = acc[i][j + 3] + b[o + 3];
                *(float4*)&Y[(size_t)r * DD + o] = ov;
            }
        }
    } else if (MODE == 1) {
#pragma unroll
        for (int i = 0; i < 8; ++i) {
            const int r = r0 + ty * 8 + i;
            bf16x8 hi, lo;
#pragma unroll
            for (int j = 0; j < 8; ++j) {
                const float v = acc[i][j] + b[o0 + tx * 8 + j];
                const unsigned short h = f2bf(v);
                hi[j] = (short)h;
                lo[j] = (short)f2bf(v - bf2f(h));
            }
            *(bf16x8*)&Yhi[(size_t)r * DD + o0 + tx * 8] = hi;
            *(bf16x8*)&Ylo[(size_t)r * DD + o0 + tx * 8] = lo;
        }
    } else {
#pragma unroll
        for (int j = 0; j < 8; ++j) {
            const int o = o0 + tx * 8 + j;
            const float bo = b[o];
            bf16x8 hi, lo;
#pragma unroll
            for (int i = 0; i < 8; ++i) {
                const float v = acc[i][j] + bo;
                const unsigned short hh = f2bf(v);
                hi[i] = (short)hh;
                lo[i] = (short)f2bf(v - bf2f(hh));
            }
            *(bf16x8*)&Yhi[(size_t)o * nrows + r0 + ty * 8] = hi;
            *(bf16x8*)&Ylo[(size_t)o * nrows + r0 + ty * 8] = lo;
        }
    }
}

// ---------------------------------------------------------------------------
// MFMA flash attention, split-bf16 (hi/lo, 3-product) for QK^T and PV.
// Block: 256 thr = 4 waves, each wave owns 16 q rows. KT=64 keys/iter.
// LDS XOR-swizzled (k ^ ((row&7)<<3)) everywhere; double-buffered K/V;
// reg-staged global->LDS (issue loads early, ds_write late); 1 barrier/iter.
// ---------------------------------------------------------------------------
#define QT 64
#define KT 64
#define NT (NLK / KT)

__global__ __launch_bounds__(256) void attn_mfma(const short* __restrict__ qhi,
                                                 const short* __restrict__ qlo,
                                                 const short* __restrict__ khi,
                                                 const short* __restrict__ klo,
                                                 const short* __restrict__ vthi,
                                                 const short* __restrict__ vtlo,
                                                 const float* __restrict__ bias,
                                                 const int* __restrict__ mask,
                                                 float* __restrict__ ao)
{
    __shared__ __align__(16) short ksh[2][KT * HD];
    __shared__ __align__(16) short ksl[2][KT * HD];
    __shared__ __align__(16) short vth[2][HD * KT];
    __shared__ __align__(16) short vtl[2][HD * KT];
    __shared__ __align__(16) short psh[QT * KT];
    __shared__ __align__(16) short psl[QT * KT];

    // flat grid 256: h = b&7 so same-head blocks (sharing K/V) sit on one XCD
    const int h  = blockIdx.x & 7;
    const int q0 = (blockIdx.x >> 3) * QT;
    const int t    = threadIdx.x;
    const int wid  = t >> 6;
    const int lane = t & 63;
    const int g = lane >> 4;
    const int c = lane & 15;

    // Q A-fragments, held in registers for the whole kernel
    bf16x8 qah[2], qal[2];
    {
        const size_t qr = (size_t)(q0 + wid * 16 + c) * DD + h * HD;
        qah[0] = *(const bf16x8*)&qhi[qr + 8 * g];
        qah[1] = *(const bf16x8*)&qhi[qr + 32 + 8 * g];
        qal[0] = *(const bf16x8*)&qlo[qr + 8 * g];
        qal[1] = *(const bf16x8*)&qlo[qr + 32 + 8 * g];
    }

    // staging: thread covers rows kr0 and kr0+32 (d-rows for V), cols db0..db0+7
    const int kr0 = t >> 3;
    const int db0 = (t & 7) * 8;
    const int swst = ((kr0 & 7) << 3);  // same for kr0+32

    bf16x8 rkh[2], rkl[2], rvh[2], rvl[2];

    auto stage_load = [&](int kt) {
        rkh[0] = *(const bf16x8*)&khi[(size_t)(kt + kr0) * DD + h * HD + db0];
        rkh[1] = *(const bf16x8*)&khi[(size_t)(kt + kr0 + 32) * DD + h * HD + db0];
        rkl[0] = *(const bf16x8*)&klo[(size_t)(kt + kr0) * DD + h * HD + db0];
        rkl[1] = *(const bf16x8*)&klo[(size_t)(kt + kr0 + 32) * DD + h * HD + db0];
        rvh[0] = *(const bf16x8*)&vthi[(size_t)(h * HD + kr0) * NLK + kt + db0];
        rvh[1] = *(const bf16x8*)&vthi[(size_t)(h * HD + kr0 + 32) * NLK + kt + db0];
        rvl[0] = *(const bf16x8*)&vtlo[(size_t)(h * HD + kr0) * NLK + kt + db0];
        rvl[1] = *(const bf16x8*)&vtlo[(size_t)(h * HD + kr0 + 32) * NLK + kt + db0];
    };
    auto stage_write = [&](int buf) {
        const int i0 = kr0 * HD + (db0 ^ swst);
        const int i1 = (kr0 + 32) * HD + (db0 ^ swst);
        *(bf16x8*)&ksh[buf][i0] = rkh[0];
        *(bf16x8*)&ksh[buf][i1] = rkh[1];
        *(bf16x8*)&ksl[buf][i0] = rkl[0];
        *(bf16x8*)&ksl[buf][i1] = rkl[1];
        *(bf16x8*)&vth[buf][i0] = rvh[0];
        *(bf16x8*)&vth[buf][i1] = rvh[1];
        *(bf16x8*)&vtl[buf][i0] = rvl[0];
        *(bf16x8*)&vtl[buf][i1] = rvl[1];
    };

    f32x4 acco[4];
    float m_[4], l_[4];
#pragma unroll
    for (int n = 0; n < 4; ++n) { acco[n] = (f32x4){0.f, 0.f, 0.f, 0.f}; }
#pragma unroll
    for (int r = 0; r < 4; ++r) { m_[r] = -1e30f; l_[r] = 0.f; }

    stage_load(0);
    stage_write(0);
    int cur = 0;

    for (int it = 0; it < NT; ++it) {
        const int kt = it * KT;
        __syncthreads();

        if (it + 1 < NT) stage_load(kt + KT);

        // bias + mask for this tile (L2/L3-resident, overlap with MFMA)
        float br[4][4];
        int mk[4];
#pragma unroll
        for (int j = 0; j < 4; ++j) mk[j] = mask[kt + 16 * j + c];
#pragma unroll
        for (int r = 0; r < 4; ++r) {
            const size_t bro = (size_t)(q0 + wid * 16 + 4 * g + r) * NLK + kt + c;
#pragma unroll
            for (int j = 0; j < 4; ++j) br[r][j] = bias[bro + 16 * j];
        }

        // ---- QK^T: sc[j] covers k-cols 16j..16j+15 for this wave's 16 q ----
        f32x4 sc[4];
#pragma unroll
        for (int j = 0; j < 4; ++j) sc[j] = (f32x4){0.f, 0.f, 0.f, 0.f};
        const int swc = ((c & 7) << 3);
#pragma unroll
        for (int j = 0; j < 4; ++j) {
            const int krow = (16 * j + c) * HD;
#pragma unroll
            for (int s = 0; s < 2; ++s) {
                const int off = krow + ((32 * s + 8 * g) ^ swc);
                const bf16x8 bh = *(const bf16x8*)&ksh[cur][off];
                const bf16x8 bl = *(const bf16x8*)&ksl[cur][off];
                sc[j] = MFMA16(qah[s], bh, sc[j]);
                sc[j] = MFMA16(qah[s], bl, sc[j]);
                sc[j] = MFMA16(qal[s], bh, sc[j]);
            }
        }

        float fm[4];
#pragma unroll
        for (int j = 0; j < 4; ++j) fm[j] = mk[j] ? -10000.f : 0.f;
#pragma unroll
        for (int j = 0; j < 4; ++j)
#pragma unroll
            for (int r = 0; r < 4; ++r)
                sc[j][r] = fmaf(sc[j][r], 0.125f, br[r][j] + fm[j]);

        // ---- online softmax (row q = 4g+r; 16 lanes of same g share a row) ----
#pragma unroll
        for (int r = 0; r < 4; ++r) {
            float tm = fmaxf(fmaxf(sc[0][r], sc[1][r]), fmaxf(sc[2][r], sc[3][r]));
            tm = fmaxf(tm, __shfl_xor(tm, 1));
            tm = fmaxf(tm, __shfl_xor(tm, 2));
            tm = fmaxf(tm, __shfl_xor(tm, 4));
            tm = fmaxf(tm, __shfl_xor(tm, 8));
            const float mn = fmaxf(m_[r], tm);
            const float al = __expf(m_[r] - mn);
            m_[r] = mn;
            float pv[4];
            float ts = 0.f;
#pragma unroll
            for (int j = 0; j < 4; ++j) {
                pv[j] = __expf(sc[j][r] - mn);
                ts += pv[j];
            }
            ts += __shfl_xor(ts, 1);
            ts += __shfl_xor(ts, 2);
            ts += __shfl_xor(ts, 4);
            ts += __shfl_xor(ts, 8);
            l_[r] = l_[r] * al + ts;
#pragma unroll
            for (int n = 0; n < 4; ++n) acco[n][r] *= al;

            const int qrow = wid * 16 + 4 * g + r;
            const int sw = ((qrow & 7) << 3);
#pragma unroll
            for (int j = 0; j < 4; ++j) {
                const unsigned short hh = f2bf(pv[j]);
                const unsigned short ll = f2bf(pv[j] - bf2f(hh));
                const int idx = qrow * KT + ((16 * j + c) ^ sw);
                psh[idx] = (short)hh;
                psl[idx] = (short)ll;
            }
        }

        // ---- PV: acco[n] covers d-cols 16n..16n+15 (same-wave LDS RAW, no barrier) ----
        bf16x8 pah[2], pal[2];
        {
            const int qr = (wid * 16 + c) * KT;
            pah[0] = *(const bf16x8*)&psh[qr + ((8 * g) ^ swc)];
            pah[1] = *(const bf16x8*)&psh[qr + ((32 + 8 * g) ^ swc)];
            pal[0] = *(const bf16x8*)&psl[qr + ((8 * g) ^ swc)];
            pal[1] = *(const bf16x8*)&psl[qr + ((32 + 8 * g) ^ swc)];
        }
#pragma unroll
        for (int n = 0; n < 4; ++n) {
            const int drow = (16 * n + c) * KT;
#pragma unroll
            for (int s = 0; s < 2; ++s) {
                const int off = drow + ((32 * s + 8 * g) ^ swc);
                const bf16x8 vh = *(const bf16x8*)&vth[cur][off];
                const bf16x8 vl = *(const bf16x8*)&vtl[cur][off];
                acco[n] = MFMA16(pah[s], vh, acco[n]);
                acco[n] = MFMA16(pah[s], vl, acco[n]);
                acco[n] = MFMA16(pal[s], vh, acco[n]);
            }
        }

        if (it + 1 < NT) stage_write(cur ^ 1);
        cur ^= 1;
    }

    // epilogue: ao[q][h*64 + d]
#pragma unroll
    for (int r = 0; r < 4; ++r) {
        const float inv = 1.f / l_[r];
        const size_t row = (size_t)(q0 + wid * 16 + 4 * g + r) * DD + h * HD;
#pragma unroll
        for (int n = 0; n < 4; ++n)
            ao[row + 16 * n + c] = acco[n][r] * inv;
    }
}

extern "C" void kernel_launch(void* const* d_in, const int* in_sizes, int n_in,
                              void* d_out, int out_size, void* d_ws, size_t ws_size,
                              hipStream_t stream)
{
    (void)in_sizes; (void)n_in; (void)out_size; (void)ws_size;
    const float* Q    = (const float*)d_in[0];
    const float* K    = (const float*)d_in[1];
    const float* V    = (const float*)d_in[2];
    const int*   mask = (const int*)d_in[3];
    const float* bias = (const float*)d_in[4];
    const float* Win  = (const float*)d_in[5];
    const float* bin  = (const float*)d_in[6];
    const float* Wout = (const float*)d_in[7];
    const float* bout = (const float*)d_in[8];
    float* out = (float*)d_out;

    // workspace: bf16 hi/lo q,k,v^T + f32 ao  (~40 MB, same as round-1 layout)
    short* qhi_  = (short*)d_ws;
    short* qlo_  = qhi_  + (size_t)NLQ * DD;
    short* khi_  = qlo_  + (size_t)NLQ * DD;
    short* klo_  = khi_  + (size_t)NLK * DD;
    short* vthi_ = klo_  + (size_t)NLK * DD;
    short* vtlo_ = vthi_ + (size_t)NLK * DD;
    float* ao_   = (float*)(vtlo_ + (size_t)NLK * DD);

    gemm_wt<1><<<dim3(NLQ / 128, 4), 256, 0, stream>>>(Q, Win,               bin,           nullptr, qhi_,  qlo_,  NLQ);
    gemm_wt<1><<<dim3(NLK / 128, 4), 256, 0, stream>>>(K, Win + DD * DD,     bin + DD,      nullptr, khi_,  klo_,  NLK);
    gemm_wt<2><<<dim3(NLK / 128, 4), 256, 0, stream>>>(V, Win + 2 * DD * DD, bin + 2 * DD,  nullptr, vthi_, vtlo_, NLK);
    attn_mfma<<<dim3(NH * (NLQ / QT)), 256, 0, stream>>>(qhi_, qlo_, khi_, klo_, vthi_, vtlo_, bias, mask, ao_);
    gemm_wt<0><<<dim3(NLQ / 128, 4), 256, 0, stream>>>(ao_, Wout, bout, out, nullptr, nullptr, NLQ);
}